// Round 6
// baseline (251.282 us; speedup 1.0000x reference)
//
#include <hip/hip_runtime.h>
#include <math.h>

// Problem constants (fixed by setup_inputs)
constexpr int HOPS  = 3;
constexpr int VOCAB = 50257;
constexpr int DIM   = 128;
constexpr int NB    = 32;         // batch
constexpr int NM    = 512;        // story slots
constexpr int NS    = 6;          // tokens per story slot
constexpr int NT    = 128;        // trees
constexpr int NL    = 64;         // tokens per tree
constexpr int SLOTS = NM + NT;    // 640
constexpr size_t TS = (size_t)VOCAB * DIM;              // fp32 table stride in C
constexpr size_t TABSTRIDE = (size_t)NB * SLOTS * DIM;  // msum per-table stride (fp16 elems)

// fp16 compressed tables, token-interleaved: Ch[v][tab][d], tab 0..2 = C[1..3].
constexpr size_t CH_ELEMS = (size_t)VOCAB * 3 * DIM;    // 19,298,688
constexpr int NE8 = (int)(CH_ELEMS / 8);                // 2,412,336 half8 groups

typedef _Float16 half8 __attribute__((ext_vector_type(8)));
typedef _Float16 half4 __attribute__((ext_vector_type(4)));

constexpr int CONV_BLOCKS  = 2048;    // grid-stride converters
constexpr int STORY_BLOCKS = 2048;    // 8 story slots per block
constexpr int K1_BLOCKS    = CONV_BLOCKS + STORY_BLOCKS;  // interleaved even/odd
constexpr int TREE_BLOCKS  = NB * NT / 4;                 // 1024 (1 tree per wave)

__device__ __forceinline__ void addf4(float4& a, const float4& v) {
    a.x += v.x; a.y += v.y; a.z += v.z; a.w += v.w;
}

// ---------------------------------------------------------------------------
// Kernel 1 (fused, role by block parity):
//  even blocks: convert C[1..3] fp32 -> Ch fp16 interleaved [V][3][128]
//  odd  blocks: story gather straight from fp32 C (latency/MSHR-bound).
// Story: one 32-lane half per slot; lane owns float4 of the 128-dim row;
// fp32 accumulate over 6 tokens x 3 tables, fp16 msum store.
// ---------------------------------------------------------------------------
__global__ __launch_bounds__(256) void convert_story_k(
    const float* __restrict__ C, const int* __restrict__ story,
    _Float16* __restrict__ Ch, _Float16* __restrict__ msum)
{
    if (blockIdx.x & 1) {
        const int sb   = blockIdx.x >> 1;
        const int wave = threadIdx.x >> 6, lane = threadIdx.x & 63;
        const int h = lane >> 5, l32 = lane & 31;
        const int g = sb * 8 + wave * 2 + h;          // b*NM + slot
        const int b = g >> 9, slot = g & (NM - 1);

        const int* idx = story + (size_t)g * NS;
        const int tokv = (l32 < NS) ? idx[l32] : 0;

        const float* Cb = C + TS + (size_t)l32 * 4;   // table 1 base, my dims
        float4 a0 = {0,0,0,0}, a1 = {0,0,0,0}, a2 = {0,0,0,0};
        #pragma unroll
        for (int i = 0; i < NS; ++i) {
            const int s = __shfl(tokv, h * 32 + i);
            const float* p = Cb + (size_t)s * DIM;
            addf4(a0, *(const float4*)(p));
            addf4(a1, *(const float4*)(p + TS));
            addf4(a2, *(const float4*)(p + 2 * TS));
        }
        half4 h0, h1, h2;
        h0[0]=(_Float16)a0.x; h0[1]=(_Float16)a0.y; h0[2]=(_Float16)a0.z; h0[3]=(_Float16)a0.w;
        h1[0]=(_Float16)a1.x; h1[1]=(_Float16)a1.y; h1[2]=(_Float16)a1.z; h1[3]=(_Float16)a1.w;
        h2[0]=(_Float16)a2.x; h2[1]=(_Float16)a2.y; h2[2]=(_Float16)a2.z; h2[3]=(_Float16)a2.w;
        const size_t o = ((size_t)b * SLOTS + slot) * DIM + l32 * 4;
        *(half4*)(msum + o)                 = h0;
        *(half4*)(msum + o + TABSTRIDE)     = h1;
        *(half4*)(msum + o + 2 * TABSTRIDE) = h2;
    } else {
        const int cb = blockIdx.x >> 1;
        for (int e8 = cb * 256 + threadIdx.x; e8 < NE8; e8 += CONV_BLOCKS * 256) {
            const size_t base = (size_t)e8 * 8;
            const size_t v    = base / 384;
            const int    rem  = (int)(base % 384);
            const int    tab  = rem >> 7;             // 0..2
            const int    d    = rem & 127;            // 8-aligned
            const float* src = C + (size_t)(1 + tab) * TS + v * DIM + d;
            float4 f0 = *(const float4*)(src);
            float4 f1 = *(const float4*)(src + 4);
            half8 h;
            h[0]=(_Float16)f0.x; h[1]=(_Float16)f0.y; h[2]=(_Float16)f0.z; h[3]=(_Float16)f0.w;
            h[4]=(_Float16)f1.x; h[5]=(_Float16)f1.y; h[6]=(_Float16)f1.z; h[7]=(_Float16)f1.w;
            *(half8*)(Ch + base) = h;
        }
    }
}

// ---------------------------------------------------------------------------
// Tree gather from fp16 Ch: one tree per wave; 4 quarters split the 64
// tokens (16 each); lane l16 owns dims [l16*8, l16*8+8); cross-quarter
// shfl-xor reduction; quarter 0 writes.
// ---------------------------------------------------------------------------
__global__ __launch_bounds__(256) void tree_gather(
    const _Float16* __restrict__ Ch, const int* __restrict__ kb,
    _Float16* __restrict__ msum)
{
    const int wave = threadIdx.x >> 6, lane = threadIdx.x & 63;
    const int q = lane >> 4, l16 = lane & 15;
    const int g = blockIdx.x * 4 + wave;              // b*NT + tree
    const int b = g >> 7, tr = g & (NT - 1);

    const int tok = kb[(size_t)g * NL + lane];        // coalesced 64-token load

    float a0[8] = {0,0,0,0,0,0,0,0};
    float a1[8] = {0,0,0,0,0,0,0,0};
    float a2[8] = {0,0,0,0,0,0,0,0};

    #pragma unroll
    for (int i = 0; i < 16; ++i) {
        const int s = __shfl(tok, (lane & 48) + i);   // token q*16+i of my tree
        const _Float16* p = Ch + (size_t)s * (3 * DIM) + l16 * 8;
        half8 v0 = *(const half8*)(p);
        half8 v1 = *(const half8*)(p + DIM);
        half8 v2 = *(const half8*)(p + 2 * DIM);
        #pragma unroll
        for (int j = 0; j < 8; ++j) {
            a0[j] += (float)v0[j];
            a1[j] += (float)v1[j];
            a2[j] += (float)v2[j];
        }
    }
    // reduce the 4 quarter-partials (lanes differ only in q bits 4..5)
    #pragma unroll
    for (int j = 0; j < 8; ++j) {
        a0[j] += __shfl_xor(a0[j], 16); a0[j] += __shfl_xor(a0[j], 32);
        a1[j] += __shfl_xor(a1[j], 16); a1[j] += __shfl_xor(a1[j], 32);
        a2[j] += __shfl_xor(a2[j], 16); a2[j] += __shfl_xor(a2[j], 32);
    }
    if (q == 0) {
        half8 h0, h1, h2;
        #pragma unroll
        for (int j = 0; j < 8; ++j) {
            h0[j] = (_Float16)a0[j]; h1[j] = (_Float16)a1[j]; h2[j] = (_Float16)a2[j];
        }
        const size_t o = ((size_t)b * SLOTS + NM + tr) * DIM + l16 * 8;
        *(half8*)(msum + o)                 = h0;
        *(half8*)(msum + o + TABSTRIDE)     = h1;
        *(half8*)(msum + o + 2 * TABSTRIDE) = h2;
    }
}

// ---------------------------------------------------------------------------
// Fused hop chain: one block per batch element, all 3 hops in-block.
// Layout everywhere: quarter rg = t>>4 owns rows {rg, rg+16, ...}; lane
// l16 = t&15 owns dims [l16*8, l16*8+8) (half8 = 256 B/row coalesced).
// hop0: u = mean of tab0 rows (softmax(0) uniform). hops 1..2: scores ->
// softmax -> weighted sum, u updated in LDS. fp32 accumulation throughout.
// ---------------------------------------------------------------------------
__global__ __launch_bounds__(256) void hops_fused(
    const _Float16* __restrict__ msum, float* __restrict__ out)
{
    const int b = blockIdx.x, t = threadIdx.x;
    const int rg = t >> 4, l16 = t & 15, wv = t >> 6, ln = t & 63;
    __shared__ float u_s[DIM];
    __shared__ float probs[SLOTS];
    __shared__ float part[16][DIM + 4];   // +4 pad: rg stride 132 -> 4*rg bank skew
    __shared__ float red[4];

    const _Float16* base = msum + (size_t)b * SLOTS * DIM;

    // ---- hop 0: u = (1/SLOTS) * sum of tab0 rows ----
    {
        float acc[8] = {0,0,0,0,0,0,0,0};
        for (int m = rg; m < SLOTS; m += 16) {
            half8 v = *(const half8*)(base + (size_t)m * DIM + l16 * 8);
            #pragma unroll
            for (int j = 0; j < 8; ++j) acc[j] += (float)v[j];
        }
        #pragma unroll
        for (int j = 0; j < 8; ++j) part[rg][l16 * 8 + j] = acc[j];
        __syncthreads();
        if (t < DIM) {
            float s = 0.f;
            #pragma unroll
            for (int r = 0; r < 16; ++r) s += part[r][t];
            u_s[t] = s * (1.f / SLOTS);
        }
        __syncthreads();
    }

    // ---- hops 1..2 ----
    for (int hop = 1; hop < HOPS; ++hop) {
        const _Float16* mA = base + (size_t)(hop - 1) * TABSTRIDE;
        const _Float16* mC = base + (size_t)hop * TABSTRIDE;

        // scores: raw dot(mA[m], u) -> probs[m]
        for (int m = rg; m < SLOTS; m += 16) {
            half8 v = *(const half8*)(mA + (size_t)m * DIM + l16 * 8);
            float d = 0.f;
            #pragma unroll
            for (int j = 0; j < 8; ++j) d = fmaf((float)v[j], u_s[l16 * 8 + j], d);
            d += __shfl_xor(d, 1); d += __shfl_xor(d, 2);
            d += __shfl_xor(d, 4); d += __shfl_xor(d, 8);
            if (l16 == 0) probs[m] = d;
        }
        __syncthreads();                 // raw scores visible

        // block softmax: probs -> exp(s - max), inv = 1/sum
        float s0 = probs[t], s1 = probs[t + 256];
        float s2 = (t < SLOTS - 512) ? probs[t + 512] : -INFINITY;
        float lmax = fmaxf(fmaxf(s0, s1), s2);
        #pragma unroll
        for (int off = 32; off > 0; off >>= 1) lmax = fmaxf(lmax, __shfl_xor(lmax, off));
        if (ln == 0) red[wv] = lmax;
        __syncthreads();                 // red(max) visible; raw reads all done
        lmax = fmaxf(fmaxf(red[0], red[1]), fmaxf(red[2], red[3]));
        __syncthreads();                 // red free for reuse
        float e0 = expf(s0 - lmax), e1 = expf(s1 - lmax);
        float e2 = (t < SLOTS - 512) ? expf(s2 - lmax) : 0.f;
        probs[t] = e0; probs[t + 256] = e1;
        if (t < SLOTS - 512) probs[t + 512] = e2;
        float lsum = e0 + e1 + e2;
        #pragma unroll
        for (int off = 32; off > 0; off >>= 1) lsum += __shfl_xor(lsum, off);
        if (ln == 0) red[wv] = lsum;
        __syncthreads();                 // exp probs + red(sum) visible
        const float inv = 1.0f / (red[0] + red[1] + red[2] + red[3]);

        // weighted sum: u += inv * sum_m probs[m] * mC[m]
        float acc[8] = {0,0,0,0,0,0,0,0};
        for (int m = rg; m < SLOTS; m += 16) {
            const float p = probs[m];
            half8 v = *(const half8*)(mC + (size_t)m * DIM + l16 * 8);
            #pragma unroll
            for (int j = 0; j < 8; ++j) acc[j] = fmaf(p, (float)v[j], acc[j]);
        }
        #pragma unroll
        for (int j = 0; j < 8; ++j) part[rg][l16 * 8 + j] = acc[j];
        __syncthreads();
        if (t < DIM) {
            float s = 0.f;
            #pragma unroll
            for (int r = 0; r < 16; ++r) s += part[r][t];
            u_s[t] += s * inv;
        }
        __syncthreads();
    }

    if (t < DIM) out[b * DIM + t] = u_s[t];
}

extern "C" void kernel_launch(void* const* d_in, const int* in_sizes, int n_in,
                              void* d_out, int out_size, void* d_ws, size_t ws_size,
                              hipStream_t stream) {
    const float* C     = (const float*)d_in[0];   // [4][VOCAB][DIM] fp32
    const int*   story = (const int*)d_in[1];     // [32][512][6]
    const int*   kb    = (const int*)d_in[2];     // [32][128][64]
    float*       out   = (float*)d_out;           // [32][128] fp32

    _Float16* Ch   = (_Float16*)d_ws;             // [V][3][128] fp16 = 36.8 MiB
    _Float16* msum = Ch + CH_ELEMS;               // [3][NB][SLOTS][128] fp16 = 15 MiB

    convert_story_k<<<K1_BLOCKS, 256, 0, stream>>>(C, story, Ch, msum);
    tree_gather<<<TREE_BLOCKS, 256, 0, stream>>>(Ch, kb, msum);
    hops_fused<<<NB, 256, 0, stream>>>(msum, out);
}

// Round 7
// 212.504 us; speedup vs baseline: 1.1825x; 1.1825x over previous
//
#include <hip/hip_runtime.h>
#include <math.h>

// Problem constants (fixed by setup_inputs)
constexpr int HOPS  = 3;
constexpr int VOCAB = 50257;
constexpr int DIM   = 128;
constexpr int NB    = 32;         // batch
constexpr int NM    = 512;        // story slots
constexpr int NS    = 6;          // tokens per story slot
constexpr int NT    = 128;        // trees
constexpr int NL    = 64;         // tokens per tree
constexpr int SLOTS = NM + NT;    // 640
constexpr size_t TS = (size_t)VOCAB * DIM;              // fp32 table stride in C
constexpr size_t TABSTRIDE = (size_t)NB * SLOTS * DIM;  // msum per-table stride (fp16 elems)

// fp16 compressed tables, token-interleaved: Ch[v][tab][d], tab 0..2 = C[1..3].
constexpr size_t CH_ELEMS = (size_t)VOCAB * 3 * DIM;    // 19,298,688
constexpr int NE8 = (int)(CH_ELEMS / 8);                // 2,412,336 half8 groups

typedef _Float16 half8 __attribute__((ext_vector_type(8)));
typedef _Float16 half4 __attribute__((ext_vector_type(4)));

constexpr int CONV_BLOCKS  = 2048;    // grid-stride converters
constexpr int STORY_BLOCKS = 2048;    // 8 story slots per block
constexpr int K1_BLOCKS    = CONV_BLOCKS + STORY_BLOCKS;  // interleaved even/odd
constexpr int TREE_BLOCKS  = NB * NT / 4;                 // 1024 (1 tree per wave)

__device__ __forceinline__ void addf4(float4& a, const float4& v) {
    a.x += v.x; a.y += v.y; a.z += v.z; a.w += v.w;
}

// ---------------------------------------------------------------------------
// Kernel 1 (fused, role by block parity):
//  even blocks: convert C[1..3] fp32 -> Ch fp16 interleaved [V][3][128]
//  odd  blocks: story gather straight from fp32 C (latency/MSHR-bound).
// ---------------------------------------------------------------------------
__global__ __launch_bounds__(256) void convert_story_k(
    const float* __restrict__ C, const int* __restrict__ story,
    _Float16* __restrict__ Ch, _Float16* __restrict__ msum)
{
    if (blockIdx.x & 1) {
        const int sb   = blockIdx.x >> 1;
        const int wave = threadIdx.x >> 6, lane = threadIdx.x & 63;
        const int h = lane >> 5, l32 = lane & 31;
        const int g = sb * 8 + wave * 2 + h;          // b*NM + slot
        const int b = g >> 9, slot = g & (NM - 1);

        const int* idx = story + (size_t)g * NS;
        const int tokv = (l32 < NS) ? idx[l32] : 0;

        const float* Cb = C + TS + (size_t)l32 * 4;   // table 1 base, my dims
        float4 a0 = {0,0,0,0}, a1 = {0,0,0,0}, a2 = {0,0,0,0};
        #pragma unroll
        for (int i = 0; i < NS; ++i) {
            const int s = __shfl(tokv, h * 32 + i);
            const float* p = Cb + (size_t)s * DIM;
            addf4(a0, *(const float4*)(p));
            addf4(a1, *(const float4*)(p + TS));
            addf4(a2, *(const float4*)(p + 2 * TS));
        }
        half4 h0, h1, h2;
        h0[0]=(_Float16)a0.x; h0[1]=(_Float16)a0.y; h0[2]=(_Float16)a0.z; h0[3]=(_Float16)a0.w;
        h1[0]=(_Float16)a1.x; h1[1]=(_Float16)a1.y; h1[2]=(_Float16)a1.z; h1[3]=(_Float16)a1.w;
        h2[0]=(_Float16)a2.x; h2[1]=(_Float16)a2.y; h2[2]=(_Float16)a2.z; h2[3]=(_Float16)a2.w;
        const size_t o = ((size_t)b * SLOTS + slot) * DIM + l32 * 4;
        *(half4*)(msum + o)                 = h0;
        *(half4*)(msum + o + TABSTRIDE)     = h1;
        *(half4*)(msum + o + 2 * TABSTRIDE) = h2;
    } else {
        const int cb = blockIdx.x >> 1;
        for (int e8 = cb * 256 + threadIdx.x; e8 < NE8; e8 += CONV_BLOCKS * 256) {
            const size_t base = (size_t)e8 * 8;
            const size_t v    = base / 384;
            const int    rem  = (int)(base % 384);
            const int    tab  = rem >> 7;             // 0..2
            const int    d    = rem & 127;            // 8-aligned
            const float* src = C + (size_t)(1 + tab) * TS + v * DIM + d;
            float4 f0 = *(const float4*)(src);
            float4 f1 = *(const float4*)(src + 4);
            half8 h;
            h[0]=(_Float16)f0.x; h[1]=(_Float16)f0.y; h[2]=(_Float16)f0.z; h[3]=(_Float16)f0.w;
            h[4]=(_Float16)f1.x; h[5]=(_Float16)f1.y; h[6]=(_Float16)f1.z; h[7]=(_Float16)f1.w;
            *(half8*)(Ch + base) = h;
        }
    }
}

// ---------------------------------------------------------------------------
// Tree gather from fp16 Ch: one tree per wave; 4 quarters split the 64
// tokens (16 each); lane l16 owns dims [l16*8, l16*8+8); cross-quarter
// shfl-xor reduction; quarter 0 writes.
// ---------------------------------------------------------------------------
__global__ __launch_bounds__(256) void tree_gather(
    const _Float16* __restrict__ Ch, const int* __restrict__ kb,
    _Float16* __restrict__ msum)
{
    const int wave = threadIdx.x >> 6, lane = threadIdx.x & 63;
    const int q = lane >> 4, l16 = lane & 15;
    const int g = blockIdx.x * 4 + wave;              // b*NT + tree
    const int b = g >> 7, tr = g & (NT - 1);

    const int tok = kb[(size_t)g * NL + lane];        // coalesced 64-token load

    float a0[8] = {0,0,0,0,0,0,0,0};
    float a1[8] = {0,0,0,0,0,0,0,0};
    float a2[8] = {0,0,0,0,0,0,0,0};

    #pragma unroll
    for (int i = 0; i < 16; ++i) {
        const int s = __shfl(tok, (lane & 48) + i);   // token q*16+i of my tree
        const _Float16* p = Ch + (size_t)s * (3 * DIM) + l16 * 8;
        half8 v0 = *(const half8*)(p);
        half8 v1 = *(const half8*)(p + DIM);
        half8 v2 = *(const half8*)(p + 2 * DIM);
        #pragma unroll
        for (int j = 0; j < 8; ++j) {
            a0[j] += (float)v0[j];
            a1[j] += (float)v1[j];
            a2[j] += (float)v2[j];
        }
    }
    // reduce the 4 quarter-partials (lanes differ only in q bits 4..5)
    #pragma unroll
    for (int j = 0; j < 8; ++j) {
        a0[j] += __shfl_xor(a0[j], 16); a0[j] += __shfl_xor(a0[j], 32);
        a1[j] += __shfl_xor(a1[j], 16); a1[j] += __shfl_xor(a1[j], 32);
        a2[j] += __shfl_xor(a2[j], 16); a2[j] += __shfl_xor(a2[j], 32);
    }
    if (q == 0) {
        half8 h0, h1, h2;
        #pragma unroll
        for (int j = 0; j < 8; ++j) {
            h0[j] = (_Float16)a0[j]; h1[j] = (_Float16)a1[j]; h2[j] = (_Float16)a2[j];
        }
        const size_t o = ((size_t)b * SLOTS + NM + tr) * DIM + l16 * 8;
        *(half8*)(msum + o)                 = h0;
        *(half8*)(msum + o + TABSTRIDE)     = h1;
        *(half8*)(msum + o + 2 * TABSTRIDE) = h2;
    }
}

// ---------------------------------------------------------------------------
// Fused hop chain: one 1024-thread block (16 waves) per batch element.
// Quarter rg = t>>4 (0..63) owns rows {rg, rg+64, ...} (10 rows); lane
// l16 = t&15 owns dims [l16*8, l16*8+8). A wave's 4 quarters read 4
// consecutive 256 B rows = 1 KB contiguous per load step.
// hop0: u = mean of tab0 rows (softmax(0) uniform). hops 1..2: scores ->
// softmax -> weighted sum, u updated in LDS. fp32 accumulation throughout.
// ---------------------------------------------------------------------------
__global__ __launch_bounds__(1024) void hops_fused(
    const _Float16* __restrict__ msum, float* __restrict__ out)
{
    const int b = blockIdx.x, t = threadIdx.x;
    const int rg = t >> 4, l16 = t & 15, wv = t >> 6, ln = t & 63;
    __shared__ float u_s[DIM];
    __shared__ float probs[SLOTS];
    __shared__ float part[64][DIM + 4];   // 33.8 KB; +4 pad -> 4*rg bank skew
    __shared__ float red[16];

    const _Float16* base = msum + (size_t)b * SLOTS * DIM;

    // ---- hop 0: u = (1/SLOTS) * sum of tab0 rows ----
    {
        float acc[8] = {0,0,0,0,0,0,0,0};
        #pragma unroll
        for (int m = rg; m < SLOTS; m += 64) {
            half8 v = *(const half8*)(base + (size_t)m * DIM + l16 * 8);
            #pragma unroll
            for (int j = 0; j < 8; ++j) acc[j] += (float)v[j];
        }
        #pragma unroll
        for (int j = 0; j < 8; ++j) part[rg][l16 * 8 + j] = acc[j];
        __syncthreads();
        if (t < DIM) {
            float s = 0.f;
            #pragma unroll
            for (int r = 0; r < 64; ++r) s += part[r][t];
            u_s[t] = s * (1.f / SLOTS);
        }
        __syncthreads();
    }

    // ---- hops 1..2 ----
    for (int hop = 1; hop < HOPS; ++hop) {
        const _Float16* mA = base + (size_t)(hop - 1) * TABSTRIDE;
        const _Float16* mC = base + (size_t)hop * TABSTRIDE;

        // scores: raw dot(mA[m], u) -> probs[m]
        #pragma unroll
        for (int m = rg; m < SLOTS; m += 64) {
            half8 v = *(const half8*)(mA + (size_t)m * DIM + l16 * 8);
            float d = 0.f;
            #pragma unroll
            for (int j = 0; j < 8; ++j) d = fmaf((float)v[j], u_s[l16 * 8 + j], d);
            d += __shfl_xor(d, 1); d += __shfl_xor(d, 2);
            d += __shfl_xor(d, 4); d += __shfl_xor(d, 8);
            if (l16 == 0) probs[m] = d;
        }
        __syncthreads();                 // raw scores visible

        // block softmax over SLOTS entries (t<SLOTS owns one)
        float s0 = (t < SLOTS) ? probs[t] : -INFINITY;
        float lmax = s0;
        #pragma unroll
        for (int off = 32; off > 0; off >>= 1) lmax = fmaxf(lmax, __shfl_xor(lmax, off));
        if (ln == 0) red[wv] = lmax;
        __syncthreads();                 // red(max) visible; raw reads all done
        lmax = red[0];
        #pragma unroll
        for (int r = 1; r < 16; ++r) lmax = fmaxf(lmax, red[r]);
        __syncthreads();                 // red free for reuse
        float e0 = (t < SLOTS) ? expf(s0 - lmax) : 0.f;
        if (t < SLOTS) probs[t] = e0;
        float lsum = e0;
        #pragma unroll
        for (int off = 32; off > 0; off >>= 1) lsum += __shfl_xor(lsum, off);
        if (ln == 0) red[wv] = lsum;
        __syncthreads();                 // exp probs + red(sum) visible
        float tot = red[0];
        #pragma unroll
        for (int r = 1; r < 16; ++r) tot += red[r];
        const float inv = 1.0f / tot;

        // weighted sum: u += inv * sum_m probs[m] * mC[m]
        float acc[8] = {0,0,0,0,0,0,0,0};
        #pragma unroll
        for (int m = rg; m < SLOTS; m += 64) {
            const float p = probs[m];
            half8 v = *(const half8*)(mC + (size_t)m * DIM + l16 * 8);
            #pragma unroll
            for (int j = 0; j < 8; ++j) acc[j] = fmaf(p, (float)v[j], acc[j]);
        }
        __syncthreads();                 // done reading probs before part reuse? (part!=probs, but keep order tight)
        #pragma unroll
        for (int j = 0; j < 8; ++j) part[rg][l16 * 8 + j] = acc[j];
        __syncthreads();
        if (t < DIM) {
            float s = 0.f;
            #pragma unroll
            for (int r = 0; r < 64; ++r) s += part[r][t];
            u_s[t] += s * inv;
        }
        __syncthreads();
    }

    if (t < DIM) out[b * DIM + t] = u_s[t];
}

extern "C" void kernel_launch(void* const* d_in, const int* in_sizes, int n_in,
                              void* d_out, int out_size, void* d_ws, size_t ws_size,
                              hipStream_t stream) {
    const float* C     = (const float*)d_in[0];   // [4][VOCAB][DIM] fp32
    const int*   story = (const int*)d_in[1];     // [32][512][6]
    const int*   kb    = (const int*)d_in[2];     // [32][128][64]
    float*       out   = (float*)d_out;           // [32][128] fp32

    _Float16* Ch   = (_Float16*)d_ws;             // [V][3][128] fp16 = 36.8 MiB
    _Float16* msum = Ch + CH_ELEMS;               // [3][NB][SLOTS][128] fp16 = 15 MiB

    convert_story_k<<<K1_BLOCKS, 256, 0, stream>>>(C, story, Ch, msum);
    tree_gather<<<TREE_BLOCKS, 256, 0, stream>>>(Ch, kb, msum);
    hops_fused<<<NB, 1024, 0, stream>>>(msum, out);
}